// Round 3
// baseline (1212.826 us; speedup 1.0000x reference)
//
#include <hip/hip_runtime.h>
#include <hip/hip_bf16.h>

using u16   = unsigned short;
using u16x8 = __attribute__((ext_vector_type(8))) unsigned short;
using s16x8 = __attribute__((ext_vector_type(8))) short;
using f32x4 = __attribute__((ext_vector_type(4))) float;

#define KPAD 136   // padded K stride (bf16 elems): 272B rows
#define EB   64    // edges per tile in edge kernel
#define BSH  8     // bucket shift for edge sort (256 srcs = 128KB PP per bucket)

// Storage permutation within each 128-col half:
//   storage pos p  <->  logical col n:  n = (p&7)*16 + (p>>3),  p = (n&15)*8 + (n>>4)
// This makes the mm_kernel MFMA output lane-contiguous for 16B stores.

__device__ __forceinline__ float bf2f(u16 u){
  unsigned int x = ((unsigned int)u) << 16;
  float f; __builtin_memcpy(&f, &x, 4); return f;
}
__device__ __forceinline__ u16 f2bf(float f){
  __hip_bfloat16 h = __float2bfloat16(f);
  u16 u; __builtin_memcpy(&u, &h, 2); return u;
}
__device__ __forceinline__ f32x4 mfma16(s16x8 a, s16x8 b, f32x4 c){
  return __builtin_amdgcn_mfma_f32_16x16x32_bf16(a, b, c, 0, 0, 0);
}
// bijective XCD swizzle (m204): contiguous logical chunks per XCD
__device__ __forceinline__ int xcd_swizzle(int bid, int nwg){
  const int q = nwg >> 3, r = nwg & 7;
  const int xcd = bid & 7, idx = bid >> 3;
  const int base = (xcd < r) ? xcd*(q+1) : r*(q+1) + (xcd - r)*q;
  return base + idx;
}

// ---------------------------------------------------------------------------
// prep: bf16 hi/lo transposed weight tiles (logical n, logical k) + K-permuted
// W2T + permuted tte rows + Wo into ws.
// ---------------------------------------------------------------------------
__global__ __launch_bounds__(256) void prep_kernel(
    const float* __restrict__ W1, const float* __restrict__ W2,
    const float* __restrict__ Wo, const float* __restrict__ Wr,
    u16* __restrict__ BTp_hi, u16* __restrict__ BTp_lo,
    u16* __restrict__ BTc_hi, u16* __restrict__ BTc_lo,
    u16* __restrict__ W2T, float* __restrict__ params)
{
  const int tid = blockIdx.x*256 + threadIdx.x;
  const int nth = gridDim.x*256;
  for (int id = tid; id < 2*256*128; id += nth){
    const int half = id >> 15;        // 0: patient k-rows, 1: condition k-rows
    const int rem  = id & 32767;
    const int k = rem >> 8;           // 0..127
    const int n = rem & 255;          // logical out col: <128 -> W1, >=128 -> Wr
    const float* W = (n < 128) ? W1 : Wr;
    const float v = W[(half*128 + k)*128 + (n & 127)];
    const u16 hi = f2bf(v);
    const u16 lo = f2bf(v - bf2f(hi));
    u16* dh = half ? BTc_hi : BTp_hi;
    u16* dl = half ? BTc_lo : BTp_lo;
    dh[n*KPAD + k] = hi;
    dl[n*KPAD + k] = lo;
  }
  // W2T[n][kstore], K permuted to match storage order of h1
  for (int id = tid; id < 128*128; id += nth){
    const int n = id & 127, kst = id >> 7;
    const int klog = (kst & 7)*16 + (kst >> 3);
    W2T[n*KPAD + kst] = f2bf(W2[klog*128 + n]);
  }
  for (int id = tid; id < 128; id += nth){
    const int nlog = (id & 7)*16 + (id >> 3);
    params[id]       = W1[256*128 + nlog];  // w1t, storage-permuted
    params[128 + id] = Wr[256*128 + nlog];  // wrt, storage-permuted
    params[256 + id] = Wo[id];              // Wo, logical order
  }
}

// ---------------------------------------------------------------------------
// mm: out[row][p] (permuted storage) = emb[row] @ Wcat (+bias), split-bf16
// 3-MFMA. 512 thr = 8 waves, 128 rows/tile. Persistent; chunked contiguous
// tiles per block; ny pairs share XCD via swizzle. 16B/lane C-stores.
// ---------------------------------------------------------------------------
__global__ __launch_bounds__(512, 4) void mm_kernel(
    const float* __restrict__ emb, int nrows, int ntiles, int nwg,
    const u16* __restrict__ BT_hi, const u16* __restrict__ BT_lo,
    const float* __restrict__ b1, const float* __restrict__ br,
    const float* __restrict__ b2, int has_bias,
    u16* __restrict__ outbuf)
{
  __shared__ u16 sbhi[128*KPAD];
  __shared__ u16 sblo[128*KPAD];
  const int t = threadIdx.x;
  const int wgid = xcd_swizzle(blockIdx.x, nwg);
  const int ny = wgid & 1;
  const int g  = wgid >> 1;
  const int ngroup = nwg >> 1;
  const int chunk = (ntiles + ngroup - 1) / ngroup;
  const int t_lo = g * chunk;
  const int t_hi = min(ntiles, t_lo + chunk);
  {
    const u16x8* gh = (const u16x8*)(BT_hi + ny*128*KPAD);
    const u16x8* gl = (const u16x8*)(BT_lo + ny*128*KPAD);
    u16x8* sh = (u16x8*)sbhi;
    u16x8* sl = (u16x8*)sblo;
    for (int i = t; i < 128*KPAD/8; i += 512){ sh[i] = gh[i]; sl[i] = gl[i]; }
  }
  __syncthreads();
  const int l = t & 63, w = t >> 6;
  const int lrow = l & 15, lk = l >> 4;
  float bias[8];
#pragma unroll
  for (int nb = 0; nb < 8; ++nb){
    const int col = ny*128 + nb*16 + lrow;   // logical col
    bias[nb] = 0.f;
    if (has_bias) bias[nb] = (col < 128) ? b1[col] : (br[col-128] + b2[col-128]);
  }
  for (int tile = t_lo; tile < t_hi; ++tile){
    const int row0 = tile*128 + w*16;
    const int arow = row0 + lrow;
    const float* aptr = emb + (size_t)(arow < nrows ? arow : 0) * 128;
    f32x4 acc[8];
#pragma unroll
    for (int i=0;i<8;++i) acc[i] = (f32x4){0.f,0.f,0.f,0.f};
#pragma unroll
    for (int ks = 0; ks < 4; ++ks){
      const int k0 = ks*32 + lk*8;
      const float4 x0 = *(const float4*)(aptr + k0);
      const float4 x1 = *(const float4*)(aptr + k0 + 4);
      const float xs[8] = {x0.x,x0.y,x0.z,x0.w,x1.x,x1.y,x1.z,x1.w};
      s16x8 ah, al;
#pragma unroll
      for (int q=0;q<8;++q){
        const u16 hi = f2bf(xs[q]);
        ah[q] = (short)hi;
        al[q] = (short)f2bf(xs[q] - bf2f(hi));
      }
#pragma unroll
      for (int nb = 0; nb < 8; ++nb){
        const int boff = (nb*16 + lrow)*KPAD + k0;
        const s16x8 bh = *(const s16x8*)(sbhi + boff);
        const s16x8 bl = *(const s16x8*)(sblo + boff);
        acc[nb] = mfma16(ah, bh, acc[nb]);
        acc[nb] = mfma16(al, bh, acc[nb]);
        acc[nb] = mfma16(ah, bl, acc[nb]);
      }
    }
    // 16B/lane stores: storage pos p = lrow*8 + nb within the ny half
#pragma unroll
    for (int r = 0; r < 4; ++r){
      const int row = row0 + lk*4 + r;
      if (row < nrows){
        u16x8 o;
#pragma unroll
        for (int nb = 0; nb < 8; ++nb) o[nb] = f2bf(acc[nb][r] + bias[nb]);
        *(u16x8*)(outbuf + (size_t)row*256 + ny*128 + lrow*8) = o;
      }
    }
  }
}

// ---------------------------------------------------------------------------
// Edge sort machinery: bucket by src>>BSH for L2-local gathers.
// ---------------------------------------------------------------------------
__global__ __launch_bounds__(256) void zero_kernel(int* __restrict__ p, int n){
  const int i = blockIdx.x*256 + threadIdx.x;
  if (i < n) p[i] = 0;
}
__global__ __launch_bounds__(256) void hist_kernel(
    const int* __restrict__ ei, int E, int* __restrict__ hist){
  for (int e = blockIdx.x*256 + threadIdx.x; e < E; e += gridDim.x*256)
    atomicAdd(&hist[ei[e] >> BSH], 1);
}
__global__ __launch_bounds__(1024) void scan_kernel(
    const int* __restrict__ hist, int n, int* __restrict__ cursor){
  __shared__ int part[1024];
  __shared__ int buf[2][1024];
  const int t = threadIdx.x;
  const int a0 = (2*t   < n) ? hist[2*t]   : 0;
  const int a1 = (2*t+1 < n) ? hist[2*t+1] : 0;
  part[t] = a0 + a1;
  buf[0][t] = a0 + a1;
  __syncthreads();
  int pb = 0;
  for (int off = 1; off < 1024; off <<= 1){
    int v = buf[pb][t];
    if (t >= off) v += buf[pb][t - off];
    buf[pb^1][t] = v;
    pb ^= 1;
    __syncthreads();
  }
  const int exc = buf[pb][t] - part[t];
  if (2*t   < n) cursor[2*t]   = exc;
  if (2*t+1 < n) cursor[2*t+1] = exc + a0;
}
__global__ __launch_bounds__(256) void scatter_kernel(
    const int* __restrict__ ei, const float* __restrict__ tte, int E,
    int* __restrict__ cursor, int4* __restrict__ quad){
  for (int e = blockIdx.x*256 + threadIdx.x; e < E; e += gridDim.x*256){
    const int s = ei[e], d = ei[E + e];
    const int pos = atomicAdd(&cursor[s >> BSH], 1);
    int4 q; q.x = s; q.y = d; q.z = __float_as_int(tte[e]); q.w = e;
    quad[pos] = q;
  }
}

// ---------------------------------------------------------------------------
// Edge kernel: persistent, 512 thr (8 waves), 64 edges/tile, contiguous
// chunked tiles per block (XCD-swizzled). W2T staged once. quad!=null ->
// src-sorted edges (L2-local gathers), else direct indices.
// ---------------------------------------------------------------------------
__global__ __launch_bounds__(512, 4) void edge_kernel(
    const int4* __restrict__ quad,
    const int* __restrict__ ei, const float* __restrict__ tte,
    const u16* __restrict__ PP, const u16* __restrict__ CC,
    const u16* __restrict__ W2T, const float* __restrict__ params,
    const float* __restrict__ bo_p, float* __restrict__ out, int E,
    int ntiles, int nwg)
{
  __shared__ u16 sW2T[128*KPAD];
  __shared__ u16 sA[EB*KPAD];
  __shared__ u16 sR[EB*KPAD];
  __shared__ float sw1t[128], swrt[128], sWo[128];
  __shared__ int ssrc[EB], sdst[EB], souti[EB];
  __shared__ float stte[EB];
  __shared__ float souts[4][EB];
  const int t = threadIdx.x;
  {
    const u16x8* g = (const u16x8*)W2T;
    u16x8* s = (u16x8*)sW2T;
    for (int i = t; i < 128*KPAD/8; i += 512) s[i] = g[i];
  }
  if (t < 128){ sw1t[t] = params[t]; swrt[t] = params[128+t]; sWo[t] = params[256+t]; }
  const float bo = bo_p[0];
  const int l = t & 63, w = t >> 6;
  const int lrow = l & 15, lk = l >> 4;
  const int rh = w & 1, ch = w >> 1;   // row-half (32 edges), col-quarter (32 cols)
  const int wgid = xcd_swizzle(blockIdx.x, nwg);
  const int chunk = (ntiles + nwg - 1) / nwg;
  const int t_lo = wgid * chunk;
  const int t_hi = min(ntiles, t_lo + chunk);

  for (int tile = t_lo; tile < t_hi; ++tile){
    const int e0 = tile * EB;
    if (t < EB){
      const int e = e0 + t;
      int s = 0, d = 0, ee = -1; float tt = 0.f;
      if (e < E){
        if (quad){ const int4 q = quad[e]; s = q.x; d = q.y; tt = __int_as_float(q.z); ee = q.w; }
        else     { s = ei[e]; d = ei[E + e]; tt = tte[e]; ee = e; }
      }
      ssrc[t] = s; sdst[t] = d; stte[t] = tt; souti[t] = ee;
    }
    __syncthreads();   // indices ready; prev tile fully consumed
    // gather + layer-1 assemble: id -> (edge e, 16B chunk c); c<16 -> h1, c>=16 -> res
#pragma unroll
    for (int i = 0; i < 4; ++i){
      const int id = i*512 + t;
      const int e = id >> 5, c = id & 31;
      const int s = ssrc[e], d = sdst[e];
      const float tt = stte[e];
      const u16x8 pv = *(const u16x8*)(PP + (size_t)s*256 + c*8);
      const u16x8 cv = *(const u16x8*)(CC + (size_t)d*256 + c*8);
      const int jj = (c & 15)*8;          // storage pos within half
      const float* wt = (c < 16) ? sw1t : swrt;
      u16x8 o;
#pragma unroll
      for (int q=0;q<8;++q){
        float v = bf2f(pv[q]) + bf2f(cv[q]) + tt * wt[jj+q];
        if (c < 16) v = fmaxf(v, 0.f);
        o[q] = f2bf(v);
      }
      u16* dst = (c < 16) ? (sA + e*KPAD + jj) : (sR + e*KPAD + jj);
      *(u16x8*)dst = o;
    }
    __syncthreads();   // sA/sR ready
    // MFMA over storage-k (order-invariant): wave -> rows rh*32..+31, cols ch*32..+31
    f32x4 acc[2][2];
#pragma unroll
    for (int mb=0;mb<2;++mb)
#pragma unroll
      for (int nb=0;nb<2;++nb) acc[mb][nb] = (f32x4){0.f,0.f,0.f,0.f};
#pragma unroll
    for (int ks=0; ks<4; ++ks){
      const int koff = ks*32 + lk*8;
      const s16x8 a0 = *(const s16x8*)(sA + (rh*32 + lrow)*KPAD + koff);
      const s16x8 a1 = *(const s16x8*)(sA + (rh*32 + 16 + lrow)*KPAD + koff);
      const s16x8 b0 = *(const s16x8*)(sW2T + (ch*32 + lrow)*KPAD + koff);
      const s16x8 b1 = *(const s16x8*)(sW2T + (ch*32 + 16 + lrow)*KPAD + koff);
      acc[0][0] = mfma16(a0, b0, acc[0][0]);
      acc[0][1] = mfma16(a0, b1, acc[0][1]);
      acc[1][0] = mfma16(a1, b0, acc[1][0]);
      acc[1][1] = mfma16(a1, b1, acc[1][1]);
    }
    // epilogue: h2 = relu(acc + res); partial = sum_col h2*Wo[col]
    float p[2][4] = {{0.f,0.f,0.f,0.f},{0.f,0.f,0.f,0.f}};
#pragma unroll
    for (int nb=0;nb<2;++nb){
      const int col = ch*32 + nb*16 + lrow;            // logical col
      const int rcs = lrow*8 + ch*2 + nb;              // storage pos of col
      const float wo = sWo[col];
#pragma unroll
      for (int mb=0;mb<2;++mb){
#pragma unroll
        for (int r=0;r<4;++r){
          const int row = rh*32 + mb*16 + lk*4 + r;
          float h2 = acc[mb][nb][r] + bf2f(sR[row*KPAD + rcs]);
          h2 = fmaxf(h2, 0.f);
          p[mb][r] += h2 * wo;
        }
      }
    }
#pragma unroll
    for (int off = 1; off < 16; off <<= 1){
#pragma unroll
      for (int mb=0;mb<2;++mb)
#pragma unroll
        for (int r=0;r<4;++r)
          p[mb][r] += __shfl_xor(p[mb][r], off, 64);
    }
    if (lrow == 0){
#pragma unroll
      for (int mb=0;mb<2;++mb)
#pragma unroll
        for (int r=0;r<4;++r)
          souts[ch][rh*32 + mb*16 + lk*4 + r] = p[mb][r];
    }
    __syncthreads();   // souts ready
    if (t < EB){
      const int ee = souti[t];
      if (ee >= 0)
        out[ee] = souts[0][t] + souts[1][t] + souts[2][t] + souts[3][t] + bo;
    }
  }
}

// ---------------------------------------------------------------------------
// Fallback (ws too small): pure fp32, 1 wave/edge. Slow but exact.
// ---------------------------------------------------------------------------
__global__ __launch_bounds__(256) void fallback_kernel(
    const float* __restrict__ pe, const float* __restrict__ ce,
    const int* __restrict__ ei, const float* __restrict__ tte,
    const float* __restrict__ W1, const float* __restrict__ b1,
    const float* __restrict__ W2, const float* __restrict__ b2,
    const float* __restrict__ Wo, const float* __restrict__ bo,
    const float* __restrict__ Wr, const float* __restrict__ br,
    float* __restrict__ out, int E)
{
  __shared__ float sh1[4][128];
  const int w = threadIdx.x >> 6, l = threadIdx.x & 63;
  const int e_raw = blockIdx.x*4 + w;
  const int e = e_raw < E ? e_raw : E-1;
  const int s = ei[e], d = ei[E + e];
  const float tt = tte[e];
  const float* xs = pe + (size_t)s*128;
  const float* xd = ce + (size_t)d*128;
  const float x0 = xs[l], x1 = xs[64+l], x2 = xd[l], x3 = xd[64+l];
  float h1a = b1[l], h1b = b1[64+l];
  float ra = br[l], rb = br[64+l];
  for (int k = 0; k < 256; ++k){
    const float xv = (k < 64) ? x0 : (k < 128) ? x1 : (k < 192) ? x2 : x3;
    const float xk = __shfl(xv, k & 63, 64);
    h1a += xk * W1[k*128 + l];
    h1b += xk * W1[k*128 + 64 + l];
    ra  += xk * Wr[k*128 + l];
    rb  += xk * Wr[k*128 + 64 + l];
  }
  h1a += tt * W1[256*128 + l];  h1b += tt * W1[256*128 + 64 + l];
  ra  += tt * Wr[256*128 + l];  rb  += tt * Wr[256*128 + 64 + l];
  sh1[w][l] = fmaxf(h1a, 0.f);
  sh1[w][64+l] = fmaxf(h1b, 0.f);
  __syncthreads();
  float h2a = b2[l] + ra, h2b = b2[64+l] + rb;
  for (int k = 0; k < 128; ++k){
    const float hk = sh1[w][k];
    h2a += hk * W2[k*128 + l];
    h2b += hk * W2[k*128 + 64 + l];
  }
  float sum = fmaxf(h2a,0.f)*Wo[l] + fmaxf(h2b,0.f)*Wo[64+l];
  for (int off = 1; off < 64; off <<= 1) sum += __shfl_xor(sum, off, 64);
  if (l == 0 && e_raw < E) out[e_raw] = sum + bo[0];
}

extern "C" void kernel_launch(void* const* d_in, const int* in_sizes, int n_in,
                              void* d_out, int out_size, void* d_ws, size_t ws_size,
                              hipStream_t stream)
{
  const float* pe  = (const float*)d_in[0];
  const float* ce  = (const float*)d_in[1];
  const int*   ei  = (const int*)d_in[2];
  const float* tte = (const float*)d_in[3];
  const float* W1  = (const float*)d_in[4];
  const float* b1  = (const float*)d_in[5];
  const float* W2  = (const float*)d_in[6];
  const float* b2  = (const float*)d_in[7];
  const float* Wo  = (const float*)d_in[8];
  const float* bo  = (const float*)d_in[9];
  const float* Wr  = (const float*)d_in[10];
  const float* br  = (const float*)d_in[11];
  float* out = (float*)d_out;
  const int E = in_sizes[3];
  const int npat  = in_sizes[0] / 128;
  const int ncond = in_sizes[1] / 128;

  char* ws = (char*)d_ws;
  const size_t sz_PP  = (size_t)npat  * 256 * 2;
  const size_t sz_CC  = (size_t)ncond * 256 * 2;
  const size_t sz_BT  = (size_t)256 * KPAD * 2;
  const size_t sz_W2T = (size_t)128 * KPAD * 2;
  const size_t off_PP = 0;
  const size_t off_CC = off_PP + sz_PP;
  const size_t off_BT = off_CC + sz_CC;
  const size_t off_W2T = off_BT + 4*sz_BT;
  const size_t off_params = off_W2T + sz_W2T;
  const size_t ws_base = off_params + 3*128*4 + 64;
  const size_t off_quad = (ws_base + 15) & ~(size_t)15;
  const int nbuck = (npat + 255) >> BSH;
  const size_t off_hist = off_quad + (size_t)E * 16;
  const size_t off_cur  = off_hist + (size_t)nbuck * 4;
  const size_t ws_sort  = off_cur + (size_t)nbuck * 4;

  if (ws_size >= ws_base){
    u16* PP     = (u16*)(ws + off_PP);
    u16* CCb    = (u16*)(ws + off_CC);
    u16* BTp_hi = (u16*)(ws + off_BT);
    u16* BTp_lo = (u16*)(ws + off_BT + sz_BT);
    u16* BTc_hi = (u16*)(ws + off_BT + 2*sz_BT);
    u16* BTc_lo = (u16*)(ws + off_BT + 3*sz_BT);
    u16* W2T    = (u16*)(ws + off_W2T);
    float* params = (float*)(ws + off_params);
    const bool do_sort = (ws_size >= ws_sort) && (nbuck <= 2048);
    int4* quad = do_sort ? (int4*)(ws + off_quad) : nullptr;

    if (do_sort){
      int* hist   = (int*)(ws + off_hist);
      int* cursor = (int*)(ws + off_cur);
      zero_kernel<<<(nbuck + 255)/256, 256, 0, stream>>>(hist, nbuck);
      hist_kernel<<<1024, 256, 0, stream>>>(ei, E, hist);
      scan_kernel<<<1, 1024, 0, stream>>>(hist, nbuck, cursor);
      scatter_kernel<<<1024, 256, 0, stream>>>(ei, tte, E, cursor, quad);
    }
    prep_kernel<<<64, 256, 0, stream>>>(W1, W2, Wo, Wr, BTp_hi, BTp_lo, BTc_hi, BTc_lo, W2T, params);
    const int ptiles = (npat + 127)/128;
    {
      const int nwg = 512;
      mm_kernel<<<nwg, 512, 0, stream>>>(pe, npat, ptiles, nwg, BTp_hi, BTp_lo, b1, br, b2, 0, PP);
    }
    const int ctiles = (ncond + 127)/128;
    {
      const int nwg = 2*ctiles < 512 ? 2*ctiles : 512;
      mm_kernel<<<nwg, 512, 0, stream>>>(ce, ncond, ctiles, nwg, BTc_hi, BTc_lo, b1, br, b2, 1, CCb);
    }
    const int etiles = (E + EB - 1)/EB;
    edge_kernel<<<512, 512, 0, stream>>>(quad, ei, tte, PP, CCb, W2T, params, bo, out, E, etiles, 512);
  } else {
    fallback_kernel<<<(E + 3)/4, 256, 0, stream>>>(pe, ce, ei, tte, W1, b1, W2, b2, Wo, bo, Wr, br, out, E);
  }
}

// Round 4
// 381.793 us; speedup vs baseline: 3.1767x; 3.1767x over previous
//
#include <hip/hip_runtime.h>
#include <hip/hip_bf16.h>

using u16   = unsigned short;
using u16x4 = __attribute__((ext_vector_type(4))) unsigned short;
using u16x8 = __attribute__((ext_vector_type(8))) unsigned short;
using s16x8 = __attribute__((ext_vector_type(8))) short;
using f32x4 = __attribute__((ext_vector_type(4))) float;

#define KPAD 136   // bf16 pad stride for edge LDS tiles (2-way-free b128 reads)
#define XP   136   // bf16 pad stride for mm x tiles
#define OP   264   // u16 pad stride for mm output bounce
#define EB   64    // edges per tile in edge kernel

__device__ __forceinline__ float bf2f(u16 u){
  unsigned int x = ((unsigned int)u) << 16;
  float f; __builtin_memcpy(&f, &x, 4); return f;
}
__device__ __forceinline__ u16 f2bf(float f){
  __hip_bfloat16 h = __float2bfloat16(f);
  u16 u; __builtin_memcpy(&u, &h, 2); return u;
}
__device__ __forceinline__ f32x4 mfma16(s16x8 a, s16x8 b, f32x4 c){
  return __builtin_amdgcn_mfma_f32_16x16x32_bf16(a, b, c, 0, 0, 0);
}

// ---------------------------------------------------------------------------
// prep: (a) W-fragment buffer WF[2][16][4][2][64][8] u16 (hi/lo split frags,
// lane&15 = n_local, l>>4 = kgrp) for the weights-stationary mm;
// (b) W2T[n][k] bf16 (logical); (c) params: w1t|wrt|Wo|biasC.
// ---------------------------------------------------------------------------
__global__ __launch_bounds__(256) void prep_kernel(
    const float* __restrict__ W1, const float* __restrict__ W2,
    const float* __restrict__ Wo, const float* __restrict__ Wr,
    const float* __restrict__ b1, const float* __restrict__ b2,
    const float* __restrict__ br,
    u16* __restrict__ WF, u16* __restrict__ W2T, float* __restrict__ params)
{
  const int tid = blockIdx.x*256 + threadIdx.x;
  const int nth = gridDim.x*256;
  // WF: id = ((((h*16+nb)*4+ks)*2+pair)*64+lane)*8+j
  for (int id = tid; id < 131072; id += nth){
    const int j    = id & 7;
    const int lane = (id >> 3) & 63;
    const int pair = (id >> 9) & 1;
    const int ks   = (id >> 10) & 3;
    const int nb   = (id >> 12) & 15;
    const int h    = (id >> 16) & 1;
    const int k = ks*32 + (lane >> 4)*8 + j;
    const int n = nb*16 + (lane & 15);
    const float v = ((n < 128) ? W1 : Wr)[(h*128 + k)*128 + (n & 127)];
    const u16 hi = f2bf(v);
    WF[id] = pair ? f2bf(v - bf2f(hi)) : hi;
  }
  for (int id = tid; id < 128*128; id += nth){
    const int k = id >> 7, n = id & 127;
    W2T[n*KPAD + k] = f2bf(W2[k*128 + n]);
  }
  for (int id = tid; id < 128; id += nth){
    params[id]       = W1[256*128 + id];      // w1t
    params[128 + id] = Wr[256*128 + id];      // wrt
    params[256 + id] = Wo[id];                // Wo
    params[384 + id]       = b1[id];          // biasC cols 0..127
    params[384 + 128 + id] = br[id] + b2[id]; // biasC cols 128..255
  }
}

// ---------------------------------------------------------------------------
// mm (weights-stationary): out[row][0..255] = emb[row] @ Wcat (+bias).
// 1024 thr = 16 waves; wave w owns output cols w*16..w*16+15 with W hi/lo
// frags resident in registers. Per 128-row tile: reg-stage x -> LDS bf16
// hi/lo (pad 136), 3-MFMA split accumulate, bounce through LDS (pad 264),
// store full 512-B rows. All global accesses linear/coalesced.
// ---------------------------------------------------------------------------
__global__ __launch_bounds__(1024, 4) void mm_kernel(
    const float* __restrict__ emb, int nrows, int ntiles,
    const u16* __restrict__ WFh,   // this half's 65536-u16 fragment block
    const float* __restrict__ bias, // 256 floats or nullptr
    u16* __restrict__ outbuf)
{
  __shared__ __align__(16) char smem_raw[2*128*XP*2];   // 69632 B
  u16* xhi = (u16*)smem_raw;              // [128][XP]
  u16* xlo = xhi + 128*XP;
  u16* sO  = (u16*)smem_raw;              // aliased after compute: [128][OP]
  const int t = threadIdx.x;
  const int l = t & 63, w = t >> 6;       // w = nb (0..15)
  const int lrow = l & 15, lq = l >> 4;
  // stationary W fragments
  s16x8 wf0h, wf0l, wf1h, wf1l, wf2h, wf2l, wf3h, wf3l;
  {
    const u16* base = WFh + w*4096 + l*8;
    wf0h = *(const s16x8*)(base +    0); wf0l = *(const s16x8*)(base +  512);
    wf1h = *(const s16x8*)(base + 1024); wf1l = *(const s16x8*)(base + 1536);
    wf2h = *(const s16x8*)(base + 2048); wf2l = *(const s16x8*)(base + 2560);
    wf3h = *(const s16x8*)(base + 3072); wf3l = *(const s16x8*)(base + 3584);
  }
  float bv[4] = {0.f, 0.f, 0.f, 0.f};
  if (bias){
#pragma unroll
    for (int r = 0; r < 4; ++r) bv[r] = bias[w*16 + lq*4 + r];
  }
  for (int tile = blockIdx.x; tile < ntiles; tile += gridDim.x){
    const int row0 = tile*128;
    __syncthreads();   // previous tile's sO fully consumed
    // stage: 128 rows x 128 f32, fully coalesced (wave instr = 2 full rows)
#pragma unroll
    for (int i = 0; i < 4; ++i){
      const int f4 = i*1024 + t;
      const int r = f4 >> 5, kc = f4 & 31;
      int grow = row0 + r; if (grow >= nrows) grow = nrows - 1;
      const float4 v = *(const float4*)(emb + (size_t)grow*128 + kc*4);
      const float vv[4] = {v.x, v.y, v.z, v.w};
      u16x4 h4, l4;
#pragma unroll
      for (int q = 0; q < 4; ++q){
        const u16 hi = f2bf(vv[q]);
        h4[q] = hi;
        l4[q] = f2bf(vv[q] - bf2f(hi));
      }
      *(u16x4*)(xhi + r*XP + kc*4) = h4;
      *(u16x4*)(xlo + r*XP + kc*4) = l4;
    }
    __syncthreads();
    // compute: acc[mb] over 8 row-blocks; D: lane&15 = m_local, lq*4+reg = n_local
    f32x4 acc[8];
#pragma unroll
    for (int mb = 0; mb < 8; ++mb) acc[mb] = (f32x4){0.f,0.f,0.f,0.f};
#pragma unroll
    for (int mb = 0; mb < 8; ++mb){
      const int mro = (mb*16 + lrow)*XP + lq*8;
      const s16x8 xh0 = *(const s16x8*)(xhi + mro +  0);
      const s16x8 xl0 = *(const s16x8*)(xlo + mro +  0);
      const s16x8 xh1 = *(const s16x8*)(xhi + mro + 32);
      const s16x8 xl1 = *(const s16x8*)(xlo + mro + 32);
      const s16x8 xh2 = *(const s16x8*)(xhi + mro + 64);
      const s16x8 xl2 = *(const s16x8*)(xlo + mro + 64);
      const s16x8 xh3 = *(const s16x8*)(xhi + mro + 96);
      const s16x8 xl3 = *(const s16x8*)(xlo + mro + 96);
      acc[mb] = mfma16(wf0h, xh0, acc[mb]);
      acc[mb] = mfma16(wf0l, xh0, acc[mb]);
      acc[mb] = mfma16(wf0h, xl0, acc[mb]);
      acc[mb] = mfma16(wf1h, xh1, acc[mb]);
      acc[mb] = mfma16(wf1l, xh1, acc[mb]);
      acc[mb] = mfma16(wf1h, xl1, acc[mb]);
      acc[mb] = mfma16(wf2h, xh2, acc[mb]);
      acc[mb] = mfma16(wf2l, xh2, acc[mb]);
      acc[mb] = mfma16(wf2h, xl2, acc[mb]);
      acc[mb] = mfma16(wf3h, xh3, acc[mb]);
      acc[mb] = mfma16(wf3l, xh3, acc[mb]);
      acc[mb] = mfma16(wf3h, xl3, acc[mb]);
    }
    __syncthreads();   // x consumed -> alias LDS as sO
    // scatter acc -> sO (+bias)
#pragma unroll
    for (int mb = 0; mb < 8; ++mb){
      const int m = mb*16 + lrow;
      u16x4 o;
#pragma unroll
      for (int r = 0; r < 4; ++r) o[r] = f2bf(acc[mb][r] + bv[r]);
      *(u16x4*)(sO + m*OP + w*16 + lq*4) = o;
    }
    __syncthreads();
    // store: full 512-B rows, 2 rows per wave instruction
#pragma unroll
    for (int i = 0; i < 4; ++i){
      const int idx = i*1024 + t;
      const int m = idx >> 5, c = idx & 31;
      const int grow = row0 + m;
      if (grow < nrows){
        const u16x8 v = *(const u16x8*)(sO + m*OP + c*8);
        *(u16x8*)(outbuf + (size_t)grow*256 + c*8) = v;
      }
    }
  }
}

// ---------------------------------------------------------------------------
// Edge kernel: persistent, 512 thr (8 waves), 64 edges/tile, grid-stride.
// W2T staged once per block. Gathers preloaded into registers (8 outstanding
// loads/thread) before convert+LDS-write. Identity storage layout.
// ---------------------------------------------------------------------------
__global__ __launch_bounds__(512, 4) void edge_kernel(
    const int* __restrict__ ei, const float* __restrict__ tte,
    const u16* __restrict__ PP, const u16* __restrict__ CC,
    const u16* __restrict__ W2T, const float* __restrict__ params,
    const float* __restrict__ bo_p, float* __restrict__ out, int E, int ntiles)
{
  __shared__ u16 sW2T[128*KPAD];
  __shared__ u16 sA[EB*KPAD];
  __shared__ u16 sR[EB*KPAD];
  __shared__ float sw1t[128], swrt[128], sWo[128];
  __shared__ int ssrc[EB], sdst[EB];
  __shared__ float stte[EB];
  __shared__ float souts[4][EB];
  const int t = threadIdx.x;
  {
    const u16x8* g = (const u16x8*)W2T;
    u16x8* s = (u16x8*)sW2T;
    for (int i = t; i < 128*KPAD/8; i += 512) s[i] = g[i];
  }
  if (t < 128){ sw1t[t] = params[t]; swrt[t] = params[128+t]; sWo[t] = params[256+t]; }
  const float bo = bo_p[0];
  const int l = t & 63, w = t >> 6;
  const int lrow = l & 15, lk = l >> 4;
  const int rh = w & 1, ch = w >> 1;   // row-half (32 edges), col-quarter (32 cols)

  for (int tile = blockIdx.x; tile < ntiles; tile += gridDim.x){
    const int e0 = tile * EB;
    if (t < EB){
      int e = e0 + t; if (e >= E) e = E - 1;
      ssrc[t] = ei[e]; sdst[t] = ei[E + e]; stte[t] = tte[e];
    }
    __syncthreads();   // indices ready; prev tile fully consumed
    // preload all gather chunks (8 independent loads in flight)
    u16x8 pv[4], cv[4];
#pragma unroll
    for (int i = 0; i < 4; ++i){
      const int id = i*512 + t;
      const int e = id >> 5, c = id & 31;
      pv[i] = *(const u16x8*)(PP + (size_t)ssrc[e]*256 + c*8);
      cv[i] = *(const u16x8*)(CC + (size_t)sdst[e]*256 + c*8);
    }
    // convert + assemble h1/res into LDS
#pragma unroll
    for (int i = 0; i < 4; ++i){
      const int id = i*512 + t;
      const int e = id >> 5, c = id & 31;
      const float tt = stte[e];
      const int jj = (c & 15)*8;
      const float* wt = (c < 16) ? sw1t : swrt;
      u16x8 o;
#pragma unroll
      for (int q = 0; q < 8; ++q){
        float v = bf2f(pv[i][q]) + bf2f(cv[i][q]) + tt * wt[jj+q];
        if (c < 16) v = fmaxf(v, 0.f);
        o[q] = f2bf(v);
      }
      u16* dst = (c < 16) ? (sA + e*KPAD + jj) : (sR + e*KPAD + jj);
      *(u16x8*)dst = o;
    }
    __syncthreads();   // sA/sR ready
    // MFMA: wave -> rows rh*32..+31, cols ch*32..+31
    f32x4 acc[2][2];
#pragma unroll
    for (int mb = 0; mb < 2; ++mb)
#pragma unroll
      for (int nb = 0; nb < 2; ++nb) acc[mb][nb] = (f32x4){0.f,0.f,0.f,0.f};
#pragma unroll
    for (int ks = 0; ks < 4; ++ks){
      const int koff = ks*32 + lk*8;
      const s16x8 a0 = *(const s16x8*)(sA + (rh*32 + lrow)*KPAD + koff);
      const s16x8 a1 = *(const s16x8*)(sA + (rh*32 + 16 + lrow)*KPAD + koff);
      const s16x8 b0 = *(const s16x8*)(sW2T + (ch*32 + lrow)*KPAD + koff);
      const s16x8 b1 = *(const s16x8*)(sW2T + (ch*32 + 16 + lrow)*KPAD + koff);
      acc[0][0] = mfma16(a0, b0, acc[0][0]);
      acc[0][1] = mfma16(a0, b1, acc[0][1]);
      acc[1][0] = mfma16(a1, b0, acc[1][0]);
      acc[1][1] = mfma16(a1, b1, acc[1][1]);
    }
    // epilogue: h2 = relu(acc + res); partial = sum_col h2*Wo[col]
    float p[2][4] = {{0.f,0.f,0.f,0.f},{0.f,0.f,0.f,0.f}};
#pragma unroll
    for (int nb = 0; nb < 2; ++nb){
      const int col = ch*32 + nb*16 + lrow;
      const float wo = sWo[col];
#pragma unroll
      for (int mb = 0; mb < 2; ++mb){
#pragma unroll
        for (int r = 0; r < 4; ++r){
          const int row = rh*32 + mb*16 + lk*4 + r;
          float h2 = acc[mb][nb][r] + bf2f(sR[row*KPAD + col]);
          h2 = fmaxf(h2, 0.f);
          p[mb][r] += h2 * wo;
        }
      }
    }
#pragma unroll
    for (int off = 1; off < 16; off <<= 1){
#pragma unroll
      for (int mb = 0; mb < 2; ++mb)
#pragma unroll
        for (int r = 0; r < 4; ++r)
          p[mb][r] += __shfl_xor(p[mb][r], off, 64);
    }
    if (lrow == 0){
#pragma unroll
      for (int mb = 0; mb < 2; ++mb)
#pragma unroll
        for (int r = 0; r < 4; ++r)
          souts[ch][rh*32 + mb*16 + lk*4 + r] = p[mb][r];
    }
    __syncthreads();   // souts ready
    if (t < EB && e0 + t < E)
      out[e0 + t] = souts[0][t] + souts[1][t] + souts[2][t] + souts[3][t] + bo;
  }
}

// ---------------------------------------------------------------------------
// Fallback (ws too small): pure fp32, 1 wave/edge. Slow but exact.
// ---------------------------------------------------------------------------
__global__ __launch_bounds__(256) void fallback_kernel(
    const float* __restrict__ pe, const float* __restrict__ ce,
    const int* __restrict__ ei, const float* __restrict__ tte,
    const float* __restrict__ W1, const float* __restrict__ b1,
    const float* __restrict__ W2, const float* __restrict__ b2,
    const float* __restrict__ Wo, const float* __restrict__ bo,
    const float* __restrict__ Wr, const float* __restrict__ br,
    float* __restrict__ out, int E)
{
  __shared__ float sh1[4][128];
  const int w = threadIdx.x >> 6, l = threadIdx.x & 63;
  const int e_raw = blockIdx.x*4 + w;
  const int e = e_raw < E ? e_raw : E-1;
  const int s = ei[e], d = ei[E + e];
  const float tt = tte[e];
  const float* xs = pe + (size_t)s*128;
  const float* xd = ce + (size_t)d*128;
  const float x0 = xs[l], x1 = xs[64+l], x2 = xd[l], x3 = xd[64+l];
  float h1a = b1[l], h1b = b1[64+l];
  float ra = br[l], rb = br[64+l];
  for (int k = 0; k < 256; ++k){
    const float xv = (k < 64) ? x0 : (k < 128) ? x1 : (k < 192) ? x2 : x3;
    const float xk = __shfl(xv, k & 63, 64);
    h1a += xk * W1[k*128 + l];
    h1b += xk * W1[k*128 + 64 + l];
    ra  += xk * Wr[k*128 + l];
    rb  += xk * Wr[k*128 + 64 + l];
  }
  h1a += tt * W1[256*128 + l];  h1b += tt * W1[256*128 + 64 + l];
  ra  += tt * Wr[256*128 + l];  rb  += tt * Wr[256*128 + 64 + l];
  sh1[w][l] = fmaxf(h1a, 0.f);
  sh1[w][64+l] = fmaxf(h1b, 0.f);
  __syncthreads();
  float h2a = b2[l] + ra, h2b = b2[64+l] + rb;
  for (int k = 0; k < 128; ++k){
    const float hk = sh1[w][k];
    h2a += hk * W2[k*128 + l];
    h2b += hk * W2[k*128 + 64 + l];
  }
  float sum = fmaxf(h2a,0.f)*Wo[l] + fmaxf(h2b,0.f)*Wo[64+l];
  for (int off = 1; off < 64; off <<= 1) sum += __shfl_xor(sum, off, 64);
  if (l == 0 && e_raw < E) out[e_raw] = sum + bo[0];
}

extern "C" void kernel_launch(void* const* d_in, const int* in_sizes, int n_in,
                              void* d_out, int out_size, void* d_ws, size_t ws_size,
                              hipStream_t stream)
{
  const float* pe  = (const float*)d_in[0];
  const float* ce  = (const float*)d_in[1];
  const int*   ei  = (const int*)d_in[2];
  const float* tte = (const float*)d_in[3];
  const float* W1  = (const float*)d_in[4];
  const float* b1  = (const float*)d_in[5];
  const float* W2  = (const float*)d_in[6];
  const float* b2  = (const float*)d_in[7];
  const float* Wo  = (const float*)d_in[8];
  const float* bo  = (const float*)d_in[9];
  const float* Wr  = (const float*)d_in[10];
  const float* br  = (const float*)d_in[11];
  float* out = (float*)d_out;
  const int E = in_sizes[3];
  const int npat  = in_sizes[0] / 128;
  const int ncond = in_sizes[1] / 128;

  char* ws = (char*)d_ws;
  const size_t sz_PP  = (size_t)npat  * 256 * 2;
  const size_t sz_CC  = (size_t)ncond * 256 * 2;
  const size_t sz_WF  = (size_t)131072 * 2;        // 2 halves x 65536 u16
  const size_t sz_W2T = (size_t)128 * KPAD * 2;
  const size_t off_PP = 0;
  const size_t off_CC = off_PP + sz_PP;
  const size_t off_WF = off_CC + sz_CC;
  const size_t off_W2T = off_WF + sz_WF;
  const size_t off_params = off_W2T + sz_W2T;
  const size_t ws_needed = off_params + 640*4;

  if (ws_size >= ws_needed){
    u16* PP     = (u16*)(ws + off_PP);
    u16* CCb    = (u16*)(ws + off_CC);
    u16* WF     = (u16*)(ws + off_WF);
    u16* W2T    = (u16*)(ws + off_W2T);
    float* params = (float*)(ws + off_params);
    prep_kernel<<<64, 256, 0, stream>>>(W1, W2, Wo, Wr, b1, b2, br, WF, W2T, params);
    const int ptiles = (npat + 127)/128;
    mm_kernel<<<512, 1024, 0, stream>>>(pe, npat, ptiles, WF, nullptr, PP);
    const int ctiles = (ncond + 127)/128;
    mm_kernel<<<ctiles, 1024, 0, stream>>>(ce, ncond, ctiles, WF + 65536, params + 384, CCb);
    const int etiles = (E + EB - 1)/EB;
    edge_kernel<<<512, 512, 0, stream>>>(ei, tte, PP, CCb, W2T, params, bo, out, E, etiles);
  } else {
    fallback_kernel<<<(E + 3)/4, 256, 0, stream>>>(pe, ce, ei, tte, W1, b1, W2, b2, Wo, bo, Wr, br, out, E);
  }
}